// Round 2
// baseline (462.106 us; speedup 1.0000x reference)
//
#include <hip/hip_runtime.h>
#include <hip/hip_bf16.h>

// HashNGramEmbedding: out[b,i,:] = (1/6) * sum_{n=3..8} E_n[hash_n(b,i), :]
// hash_n = rolling polynomial hash (Horner) over window [i-n+1 .. i], mod 100000,
// except positions i < n-1 use the raw byte tokens[b,i].
//
// R2 structure: one wave per strip of 4 consecutive positions (strip never
// crosses a batch row: 8192 % 4 == 0). Token window + hashes are wave-uniform
// (readfirstlane -> SGPR/SALU, scalar loads). 24 independent float4 gathers
// issued up front for MLP, then accumulate, then 4 coalesced 1KB stores.

#define HASH_BASE 257
#define VOCAB     100000
#define EMBED     256
#define SEQ       8192
#define POS_PER_WAVE 4
#define WAVES_PER_BLOCK 4

__global__ __launch_bounds__(64 * WAVES_PER_BLOCK) void hash_ngram_embed_kernel(
    const int* __restrict__ tokens,
    const float* __restrict__ E3, const float* __restrict__ E4,
    const float* __restrict__ E5, const float* __restrict__ E6,
    const float* __restrict__ E7, const float* __restrict__ E8,
    float* __restrict__ out, int total_pos)
{
    const int lane = threadIdx.x & 63;
    // Wave-uniform strip base, forced into SGPRs.
    const int wave_g = __builtin_amdgcn_readfirstlane(
        blockIdx.x * WAVES_PER_BLOCK + (threadIdx.x >> 6));
    const int base = wave_g * POS_PER_WAVE;          // global b*SEQ + i, %4 == 0
    if (base >= total_pos) return;

    const int i0 = base & (SEQ - 1);                  // position within row, %4 == 0

    // Token window: t[m] = tokens[base + m - 7], m = 0..10 (uniform -> s_load).
    int t[11];
#pragma unroll
    for (int m = 0; m < 11; ++m) {
        const int ii = i0 + m - 7;                    // index within row
        t[m] = (ii >= 0) ? tokens[base + m - 7] : 0;  // i0+3 <= SEQ-1 always
    }

    // Hashes for the 4 positions; all SALU (no overflow: < 100000*257+255).
    int ids[POS_PER_WAVE][6];
#pragma unroll
    for (int k = 0; k < POS_PER_WAVE; ++k) {
        const int i = i0 + k;
        const int x = t[7 + k];                       // tokens[base+k]
        int h = x;
#pragma unroll
        for (int j = 1; j < 8; ++j) {
            h = (h * HASH_BASE + t[7 + k - j]) % VOCAB;
            if (j >= 2) {
                const int n = j + 1;
                ids[k][j - 2] = (i < n - 1) ? x : h;
            }
        }
    }

    const float* tabs[6] = {E3, E4, E5, E6, E7, E8};
    const int off = lane * 4;

    // Issue all 24 gathers before accumulating (MLP).
    float4 v[POS_PER_WAVE][6];
#pragma unroll
    for (int k = 0; k < POS_PER_WAVE; ++k)
#pragma unroll
        for (int tb = 0; tb < 6; ++tb)
            v[k][tb] = *(const float4*)(tabs[tb] + (size_t)ids[k][tb] * EMBED + off);

    const float scale = 1.0f / 6.0f;
#pragma unroll
    for (int k = 0; k < POS_PER_WAVE; ++k) {
        float4 acc = v[k][0];
#pragma unroll
        for (int tb = 1; tb < 6; ++tb) {
            acc.x += v[k][tb].x; acc.y += v[k][tb].y;
            acc.z += v[k][tb].z; acc.w += v[k][tb].w;
        }
        acc.x *= scale; acc.y *= scale; acc.z *= scale; acc.w *= scale;
        *(float4*)(out + (size_t)(base + k) * EMBED + off) = acc;
    }
}

extern "C" void kernel_launch(void* const* d_in, const int* in_sizes, int n_in,
                              void* d_out, int out_size, void* d_ws, size_t ws_size,
                              hipStream_t stream)
{
    const int*   tokens = (const int*)d_in[0];
    const float* E3 = (const float*)d_in[1];
    const float* E4 = (const float*)d_in[2];
    const float* E5 = (const float*)d_in[3];
    const float* E6 = (const float*)d_in[4];
    const float* E7 = (const float*)d_in[5];
    const float* E8 = (const float*)d_in[6];
    float* out = (float*)d_out;

    const int total_pos = in_sizes[0];                // B*S = 65536
    const int pos_per_block = POS_PER_WAVE * WAVES_PER_BLOCK;   // 16
    const int blocks = (total_pos + pos_per_block - 1) / pos_per_block;

    hash_ngram_embed_kernel<<<blocks, 64 * WAVES_PER_BLOCK, 0, stream>>>(
        tokens, E3, E4, E5, E6, E7, E8, out, total_pos);
}